// Round 9
// baseline (583.479 us; speedup 1.0000x reference)
//
#include <hip/hip_runtime.h>

// CRF forward, latency-optimized: ONE WAVE per sequence, no barriers/fences.
// 256 blocks x 64 threads; lane l owns states j0=l, j1=l+64.
// E=exp(trans) in 128 VGPRs (f16). Multiplicative recurrence with STALE
// power-of-2 normalizer (feedback form):
//   w_t = (E·a_{t-1})*eL_t ; a_t = w_t*2^-P_t ; P_{t+1}=exp2(max w_t)-P_t+6
// KEY FIX (R9): all 16 ds_read_b128 of the activation vector are issued
// UPFRONT into 16 named h8 registers (64 VGPRs of buffers; ~210 total is
// free at 1 wave/SIMD). R8's VGPR_Count=136 proved the compiler held only
// one read-pair in flight -> 8 serialized ~130-cyc LDS round-trips/step.

typedef _Float16 half_t;
typedef _Float16 h2 __attribute__((ext_vector_type(2)));
typedef _Float16 h8 __attribute__((ext_vector_type(8)));

#define TB  1024
#define NUM 126
#define LBL 128

__device__ __forceinline__ float dot2(h2 a, h2 b, float c) {
  return __builtin_amdgcn_fdot2(a, b, c, false);
}

template <int U>
__device__ __forceinline__ float dotu(h8 a, h8 e, float c) {
  return dot2(__builtin_shufflevector(a, a, 2 * U, 2 * U + 1),
              __builtin_shufflevector(e, e, 2 * U, 2 * U + 1), c);
}

template <int CTRL>
__device__ __forceinline__ float dpp_max_step(float x) {
  int xi = __float_as_int(x);
  int yi = __builtin_amdgcn_update_dpp(xi, xi, CTRL, 0xF, 0xF, false);
  return fmaxf(x, __int_as_float(yi));
}

// max over all 64 lanes -> uniform (SGPR) via readlane(63)
__device__ __forceinline__ float wave_max64(float x) {
  x = dpp_max_step<0x111>(x);  // row_shr:1
  x = dpp_max_step<0x112>(x);  // row_shr:2
  x = dpp_max_step<0x114>(x);  // row_shr:4
  x = dpp_max_step<0x118>(x);  // row_shr:8
  x = dpp_max_step<0x142>(x);  // row_bcast:15
  x = dpp_max_step<0x143>(x);  // row_bcast:31
  return __int_as_float(__builtin_amdgcn_readlane(__float_as_int(x), 63));
}

__global__ __launch_bounds__(64, 1)
void crf_fwd(const float* __restrict__ logits, const int* __restrict__ labels,
             const int* __restrict__ lens, const float* __restrict__ trans,
             float* __restrict__ out)
{
  const int b  = blockIdx.x;
  const int l  = threadIdx.x;      // lane 0..63
  const int j0 = l;                // state j0 (< 126: always a real label)
  const int j1 = l + 64;           // state j1 (126,127 on lanes 62,63)
  const int off1 = (j1 < NUM) ? j1 : (NUM - 1);  // clamped col (load safety)
  const float mask1 = (j1 < NUM) ? 1.0f : 0.0f;  // value mask for eL1
  const int len = lens[b];

  __shared__ h2 a_sh[64];          // dword l = (a[l], a[l+64]), f16
  h8* a_sh8 = (h8*)a_sh;

  const float* lgbase = logits + (size_t)b * TB * NUM;
  const int*   lab    = labels + (size_t)b * TB;

  // ---- E rows (f16) in registers, permuted to the a_sh interleaved order:
  // f16 position p in a_sh holds state i(p) = (p>>1) + 64*(p&1)
  h8 E0[16], E1[16];
  {
    const float* tr0 = trans + j0 * LBL;
    const float* tr1 = trans + j1 * LBL;
    #pragma unroll
    for (int q = 0; q < 16; ++q) {
      h8 v0, v1;
      #pragma unroll
      for (int e = 0; e < 8; ++e) {
        int p = 8 * q + e;
        int i = (p >> 1) + 64 * (p & 1);
        v0[e] = (half_t)__expf(tr0[i]);
        v1[e] = (half_t)__expf(tr1[i]);
      }
      E0[q] = v0; E1[q] = v1;
    }
  }

  // ---- gold score (one-time, off the recurrence)
  float g = 0.f;
  #pragma unroll
  for (int kk = 0; kk < 16; ++kk) {
    int t = l + 64 * kk;
    if (t < len) {
      int lt = lab[t];
      int lp = (t == 0) ? (LBL - 2) : lab[t - 1];   // start state = 126
      g += lgbase[(size_t)t * NUM + lt] + trans[lt * LBL + lp];
    }
  }
  if (l == 0) g += trans[(LBL - 1) * LBL + lab[len - 1]];  // -> end
  #pragma unroll
  for (int o = 1; o < 64; o <<= 1) g += __shfl_xor(g, o);
  const float gold = g;

  // ---- a_0 = one-hot(start=126); same-wave in-order DS
  {
    h2 a_init;
    a_init[0] = (half_t)0.0f;
    a_init[1] = (half_t)((j1 == LBL - 2) ? 1.0f : 0.0f);
    a_sh[l] = a_init;
  }

  // ---- logit prefetch: rows 0..3 unconditional (buffer is full TB rows)
  float plg0[4], plg1[4];
  #pragma unroll
  for (int d = 0; d < 4; ++d) {
    plg0[d] = lgbase[(size_t)d * NUM + j0];
    plg1[d] = lgbase[(size_t)d * NUM + off1];
  }

  int   P    = 6;                  // stale scale exponent (applied this step)
  int   Kacc = 0;                  // sum of applied exponents
  int   Kout = 0;                  // Kacc at entry of last executed step
  float w0_out = 1.f, w1_out = 1.f;

#define STEP_BODY(Q0, Q1)                                                   \
  {                                                                         \
    float eL0 = __expf(Q0);                                                 \
    float eL1 = __expf(Q1) * mask1;                                         \
    /* ALL 16 broadcast reads issued upfront -> 64 VGPRs of buffers */      \
    h8 av0 = a_sh8[0],  av1 = a_sh8[1],  av2 = a_sh8[2],  av3 = a_sh8[3];   \
    h8 av4 = a_sh8[4],  av5 = a_sh8[5],  av6 = a_sh8[6],  av7 = a_sh8[7];   \
    h8 av8 = a_sh8[8],  av9 = a_sh8[9],  avA = a_sh8[10], avB = a_sh8[11];  \
    h8 avC = a_sh8[12], avD = a_sh8[13], avE = a_sh8[14], avF = a_sh8[15];  \
    float s0a = 0.f, s0b = 0.f, s1a = 0.f, s1b = 0.f;                       \
    _Pragma("unroll")                                                       \
    for (int u = 0; u < 4; ++u) {                                           \
      s0a = dotu<0>(av0, E0[0], s0a);   /* u loop is peeled below */        \
    }                                                                       \
    s0a = 0.f;  /* (dummy loop removed by opt; real sequence follows) */    \
    DOTS(av0, 0)  DOTS(av1, 1)  DOTS(av2, 2)  DOTS(av3, 3)                  \
    DOTS(av4, 4)  DOTS(av5, 5)  DOTS(av6, 6)  DOTS(av7, 7)                  \
    DOTS(av8, 8)  DOTS(av9, 9)  DOTS(avA, 10) DOTS(avB, 11)                 \
    DOTS(avC, 12) DOTS(avD, 13) DOTS(avE, 14) DOTS(avF, 15)                 \
    float w0 = (s0a + s0b) * eL0;                                           \
    float w1 = (s1a + s1b) * eL1;                                           \
    float sc = __int_as_float((127 - P) << 23);   /* 2^-P, SGPR, EXACT */   \
    h2 pk;                                                                  \
    pk[0] = (half_t)(w0 * sc);                                              \
    pk[1] = (half_t)(w1 * sc);                                              \
    a_sh[l] = pk;                    /* chain tail: add,mul,mul,cvt,write */\
    Kout = Kacc;  Kacc += P;         /* SALU side chain */                  \
    float m  = wave_max64(fmaxf(w0, w1));  /* shadow: next step's scale */  \
    int   Em = ((__float_as_int(m) >> 23) & 0xFF) - 127;                    \
    P = Em - P + 6;                                                         \
    w0_out = w0; w1_out = w1;                                               \
  }

// 8 dot2 per buffer: alternate accumulators by buffer parity (a/b)
#define DOTS(AV, Q)                                                         \
    if ((Q) & 1) {                                                          \
      s0b = dotu<0>(AV, E0[Q], s0b);  s1b = dotu<0>(AV, E1[Q], s1b);        \
      s0b = dotu<1>(AV, E0[Q], s0b);  s1b = dotu<1>(AV, E1[Q], s1b);        \
      s0b = dotu<2>(AV, E0[Q], s0b);  s1b = dotu<2>(AV, E1[Q], s1b);        \
      s0b = dotu<3>(AV, E0[Q], s0b);  s1b = dotu<3>(AV, E1[Q], s1b);        \
    } else {                                                                \
      s0a = dotu<0>(AV, E0[Q], s0a);  s1a = dotu<0>(AV, E1[Q], s1a);        \
      s0a = dotu<1>(AV, E0[Q], s0a);  s1a = dotu<1>(AV, E1[Q], s1a);        \
      s0a = dotu<2>(AV, E0[Q], s0a);  s1a = dotu<2>(AV, E1[Q], s1a);        \
      s0a = dotu<3>(AV, E0[Q], s0a);  s1a = dotu<3>(AV, E1[Q], s1a);        \
    }

  int t = 0;
  // main loop: all in-loop prefetch loads unconditional (rows clamped)
  for (; t + 4 <= len; t += 4) {
    int r0 = t + 4, r1 = t + 5, r2 = t + 6, r3 = t + 7;
    r0 = (r0 < TB) ? r0 : (TB - 1);  r1 = (r1 < TB) ? r1 : (TB - 1);
    r2 = (r2 < TB) ? r2 : (TB - 1);  r3 = (r3 < TB) ? r3 : (TB - 1);
    STEP_BODY(plg0[0], plg1[0])
    plg0[0] = lgbase[(size_t)r0 * NUM + j0];
    plg1[0] = lgbase[(size_t)r0 * NUM + off1];
    STEP_BODY(plg0[1], plg1[1])
    plg0[1] = lgbase[(size_t)r1 * NUM + j0];
    plg1[1] = lgbase[(size_t)r1 * NUM + off1];
    STEP_BODY(plg0[2], plg1[2])
    plg0[2] = lgbase[(size_t)r2 * NUM + j0];
    plg1[2] = lgbase[(size_t)r2 * NUM + off1];
    STEP_BODY(plg0[3], plg1[3])
    plg0[3] = lgbase[(size_t)r3 * NUM + j0];
    plg1[3] = lgbase[(size_t)r3 * NUM + off1];
  }
  // remainder (slots already hold rows t..t+3)
  const int rem = len - t;
  if (rem > 0) STEP_BODY(plg0[0], plg1[0])
  if (rem > 1) STEP_BODY(plg0[1], plg1[1])
  if (rem > 2) STEP_BODY(plg0[2], plg1[2])
#undef DOTS
#undef STEP_BODY

  // ---- alpha_len[j] = Kout*ln2 + log(w_len[j]); norm = logsumexp(+trans_end)
  const float LN2 = 0.6931471805599453f;
  float SigmaPrev = (float)Kout * LN2;
  float alpha0 = SigmaPrev + __logf(w0_out);   // -inf for dead states: ok
  float alpha1 = SigmaPrev + __logf(w1_out);

  float v0 = alpha0 + trans[(LBL - 1) * LBL + j0];
  float v1 = alpha1 + trans[(LBL - 1) * LBL + j1];
  float M = wave_max64(fmaxf(v0, v1));
  float p = __expf(v0 - M) + __expf(v1 - M);
  #pragma unroll
  for (int o = 1; o < 64; o <<= 1) p += __shfl_xor(p, o);
  if (l == 0) out[b] = gold - (M + __logf(p));
}

extern "C" void kernel_launch(void* const* d_in, const int* in_sizes, int n_in,
                              void* d_out, int out_size, void* d_ws, size_t ws_size,
                              hipStream_t stream) {
  const float* logits = (const float*)d_in[0];
  const int*   labels = (const int*)d_in[1];
  const int*   lens   = (const int*)d_in[2];
  const float* trans  = (const float*)d_in[3];
  float* out = (float*)d_out;
  (void)in_sizes; (void)n_in; (void)out_size; (void)d_ws; (void)ws_size;
  crf_fwd<<<256, 64, 0, stream>>>(logits, labels, lens, trans, out);
}